// Round 8
// baseline (200.116 us; speedup 1.0000x reference)
//
#include <hip/hip_runtime.h>

#define ALPHA_F 1000.0f

typedef _Float16 half8 __attribute__((ext_vector_type(8)));
typedef float floatx4 __attribute__((ext_vector_type(4)));

// ============ fused prep: W_enc/W_dec/creps splits + cnorm (unchanged) =====
__global__ __launch_bounds__(256) void prep(
    const float* __restrict__ W_enc, const float* __restrict__ W_dec,
    const float* __restrict__ creps,
    _Float16* __restrict__ Wh, _Float16* __restrict__ Wl,
    _Float16* __restrict__ Wdh,
    _Float16* __restrict__ Ch, _Float16* __restrict__ Cl,
    float* __restrict__ cnorm)
{
    const int bid = blockIdx.x;
    if (bid < 256) {
        const int q = bid * 256 + threadIdx.x;
        const int n = q & 255, k8 = q >> 8;
        const int k = k8 * 8;
        half8 h, l;
        #pragma unroll
        for (int i = 0; i < 8; ++i) {
            const float v = W_enc[(size_t)(k + i) * 256 + n] * 256.0f;
            const _Float16 hi = (_Float16)v;
            h[i] = hi;
            l[i] = (_Float16)(v - (float)hi);
        }
        const int kc = k >> 5, nt = n >> 4;
        const int lane = (n & 15) | ((k8 & 3) << 4);
        const size_t idx = (size_t)((kc * 16 + nt) * 64 + lane) * 8;
        *(half8*)(Wh + idx) = h;
        *(half8*)(Wl + idx) = l;
    } else if (bid < 512) {
        const int q = (bid - 256) * 256 + threadIdx.x;
        const int n = q & 2047, k8 = q >> 11;
        const int k = k8 * 8;
        half8 h;
        #pragma unroll
        for (int i = 0; i < 8; ++i) h[i] = (_Float16)W_dec[(size_t)(k + i) * 2048 + n];
        const int kc = k8 >> 2, nt = n >> 4;
        const int lane = (n & 15) | ((k8 & 3) << 4);
        *(half8*)(Wdh + (size_t)((kc * 128 + nt) * 64 + lane) * 8) = h;
    } else if (bid < 544) {
        const int q = (bid - 512) * 256 + threadIdx.x;
        const int n = q & 255, j8 = q >> 8;
        const int j = j8 * 8;
        half8 h, l;
        #pragma unroll
        for (int i = 0; i < 8; ++i) {
            const float v = creps[(size_t)n * 256 + j + i];
            const _Float16 hi = (_Float16)v;
            h[i] = hi;
            l[i] = (_Float16)((v - (float)hi) * 2048.0f);
        }
        const int jc = j >> 5, nt = n >> 4;
        const int lane = (n & 15) | ((j8 & 3) << 4);
        const size_t idx = (size_t)((jc * 16 + nt) * 64 + lane) * 8;
        *(half8*)(Ch + idx) = h;
        *(half8*)(Cl + idx) = l;
    } else {
        const int wid = threadIdx.x >> 6, lane = threadIdx.x & 63;
        const int row = (bid - 544) * 4 + wid;
        const float4 v = *(const float4*)(creps + (size_t)row * 256 + lane * 4);
        float s = v.x * v.x + v.y * v.y + v.z * v.z + v.w * v.w;
        #pragma unroll
        for (int off = 32; off >= 1; off >>= 1) s += __shfl_xor(s, off, 64);
        if (lane == 0) cnorm[row] = s;
    }
}

// ============ emb partials — R3-exact (B from L2, raw barriers, 64-row) =====
__global__ __launch_bounds__(256) void emb_gemm(
    const float* __restrict__ x, const _Float16* __restrict__ Wh,
    const _Float16* __restrict__ Wl, float* __restrict__ P)
{
    __shared__ _Float16 Ah[2][2048], Al[2][2048];
    const int t = threadIdx.x, lane = t & 63, w = t >> 6;
    const int kk = blockIdx.x;
    const int mb = blockIdx.y;
    const int m0 = mb * 64;

    const int am = t >> 2, q = t & 3;
    const int aoff = (((am >> 4) * 64) + ((am & 15) | (q << 4))) * 8;
    const float* xP = x + (size_t)(m0 + am) * 2048 + kk * 512 + q * 8;

    const _Float16* bhP = Wh + (size_t)((kk * 256 + w * 4) * 64 + lane) * 8;
    const _Float16* blP = Wl + (size_t)((kk * 256 + w * 4) * 64 + lane) * 8;

    floatx4 acc[4][4] = {};
    half8 bh[4], bl[4];

    {
        const float4 v0 = *(const float4*)(xP);
        const float4 v1 = *(const float4*)(xP + 4);
        const float vv[8] = {v0.x, v0.y, v0.z, v0.w, v1.x, v1.y, v1.z, v1.w};
        half8 h8, l8;
        #pragma unroll
        for (int i = 0; i < 8; ++i) {
            const _Float16 hi = (_Float16)vv[i];
            h8[i] = hi;
            l8[i] = (_Float16)(vv[i] - (float)hi);
        }
        *(half8*)(&Ah[0][aoff]) = h8;
        *(half8*)(&Al[0][aoff]) = l8;
        #pragma unroll
        for (int ni = 0; ni < 4; ++ni) {
            bh[ni] = *(const half8*)(bhP + ni * 512);
            bl[ni] = *(const half8*)(blP + ni * 512);
        }
        asm volatile("s_waitcnt lgkmcnt(0)" ::: "memory");
        __builtin_amdgcn_sched_barrier(0);
        __builtin_amdgcn_s_barrier();
    }

    #pragma unroll 2
    for (int it = 0; it < 16; ++it) {
        const int buf = it & 1;

        float4 n0, n1;
        half8 nbh[4], nbl[4];
        if (it < 15) {
            n0 = *(const float4*)(xP + (it + 1) * 32);
            n1 = *(const float4*)(xP + (it + 1) * 32 + 4);
            #pragma unroll
            for (int ni = 0; ni < 4; ++ni) {
                nbh[ni] = *(const half8*)(bhP + (size_t)(it + 1) * 8192 + ni * 512);
                nbl[ni] = *(const half8*)(blP + (size_t)(it + 1) * 8192 + ni * 512);
            }
        }

        half8 ah[4], al[4];
        #pragma unroll
        for (int s = 0; s < 4; ++s) {
            ah[s] = *(const half8*)(&Ah[buf][(s * 64 + lane) * 8]);
            al[s] = *(const half8*)(&Al[buf][(s * 64 + lane) * 8]);
        }

        #pragma unroll
        for (int mi = 0; mi < 4; ++mi) {
            #pragma unroll
            for (int ni = 0; ni < 4; ++ni) {
                acc[mi][ni] = __builtin_amdgcn_mfma_f32_16x16x32_f16(ah[mi], bl[ni], acc[mi][ni], 0, 0, 0);
                acc[mi][ni] = __builtin_amdgcn_mfma_f32_16x16x32_f16(al[mi], bh[ni], acc[mi][ni], 0, 0, 0);
                acc[mi][ni] = __builtin_amdgcn_mfma_f32_16x16x32_f16(ah[mi], bh[ni], acc[mi][ni], 0, 0, 0);
            }
        }

        if (it < 15) {
            const float vv[8] = {n0.x, n0.y, n0.z, n0.w, n1.x, n1.y, n1.z, n1.w};
            half8 h8, l8;
            #pragma unroll
            for (int i = 0; i < 8; ++i) {
                const _Float16 hi = (_Float16)vv[i];
                h8[i] = hi;
                l8[i] = (_Float16)(vv[i] - (float)hi);
            }
            *(half8*)(&Ah[buf ^ 1][aoff]) = h8;
            *(half8*)(&Al[buf ^ 1][aoff]) = l8;
            #pragma unroll
            for (int ni = 0; ni < 4; ++ni) { bh[ni] = nbh[ni]; bl[ni] = nbl[ni]; }
            asm volatile("s_waitcnt lgkmcnt(0)" ::: "memory");
            __builtin_amdgcn_sched_barrier(0);
            __builtin_amdgcn_s_barrier();
        }
    }

    float* Pk = P + (size_t)kk * 2097152;
    #pragma unroll
    for (int mi = 0; mi < 4; ++mi) {
        #pragma unroll
        for (int ni = 0; ni < 4; ++ni) {
            const int col = w * 64 + ni * 16 + (lane & 15);
            const int rowBase = m0 + mi * 16 + (lane >> 4) * 4;
            #pragma unroll
            for (int r = 0; r < 4; ++r)
                Pk[(size_t)(rowBase + r) * 256 + col] = acc[mi][ni][r];
        }
    }
}

// ============ fused finalize + dist + softmin ===============================
// Replaces finalize + dist16: per-block 16 rows; P-sum + bias + ssq + embh
// store with e held in 64 registers (lane (arow16,aoct) holds e[row][kc*32+
// aoct*8..+8] — exactly the layout dist16's embf load produced, so the
// dist-phase A-frag conversion, MFMA chains, D formula, reductions, and
// epilogue are verbatim R3-dist16). embf/enorm globals eliminated.
// Only numeric delta vs the split version: ssq reduce tree (xor 16,32 over
// lane quarters vs xor 1,2,4 over c8) — a per-row uniform D shift that
// cancels in softmax; embh bits identical.
__global__ __launch_bounds__(256) void dist_fused(
    const float* __restrict__ P, const float* __restrict__ b_enc,
    const _Float16* __restrict__ ch, const _Float16* __restrict__ cl,
    const float* __restrict__ cnorm,
    _Float16* __restrict__ ehg, float* __restrict__ out)
{
    __shared__ float D[16 * 257];
    __shared__ float ENORM[16];
    __shared__ float MINV[16], SUMV[16];
    const int t = threadIdx.x, lane = t & 63, w = t >> 6;
    const int blk = blockIdx.x;
    const int b0 = blk * 16;
    const int arow16 = lane & 15, aoct = lane >> 4;

    // ---- phase A: P-sum (order kk=0,1,2,3) + *inv + bias -> e; ssq; embh ----
    float e[8][8];
    float ssq = 0.0f;
    const float inv = 1.0f / 256.0f;
    #pragma unroll
    for (int kc = 0; kc < 8; ++kc) {
        const float* p0 = P + (size_t)(b0 + arow16) * 256 + kc * 32 + aoct * 8;
        float4 v0 = *(const float4*)(p0);
        float4 v1 = *(const float4*)(p0 + 4);
        #pragma unroll
        for (int kkp = 1; kkp < 4; ++kkp) {
            const float* pk = p0 + (size_t)kkp * 2097152;
            const float4 a0 = *(const float4*)(pk);
            const float4 a1 = *(const float4*)(pk + 4);
            v0.x += a0.x; v0.y += a0.y; v0.z += a0.z; v0.w += a0.w;
            v1.x += a1.x; v1.y += a1.y; v1.z += a1.z; v1.w += a1.w;
        }
        const float4 bb0 = *(const float4*)(b_enc + kc * 32 + aoct * 8);
        const float4 bb1 = *(const float4*)(b_enc + kc * 32 + aoct * 8 + 4);
        e[kc][0] = v0.x * inv + bb0.x;
        e[kc][1] = v0.y * inv + bb0.y;
        e[kc][2] = v0.z * inv + bb0.z;
        e[kc][3] = v0.w * inv + bb0.w;
        e[kc][4] = v1.x * inv + bb1.x;
        e[kc][5] = v1.y * inv + bb1.y;
        e[kc][6] = v1.z * inv + bb1.z;
        e[kc][7] = v1.w * inv + bb1.w;
        #pragma unroll
        for (int j = 0; j < 8; ++j) ssq += e[kc][j] * e[kc][j];
    }
    // embh store: wave w writes kc = 2w, 2w+1 (dest lane == our lane)
    #pragma unroll
    for (int kq = 0; kq < 2; ++kq) {
        const int kc = w * 2 + kq;
        half8 h;
        #pragma unroll
        for (int j = 0; j < 8; ++j) h[j] = (_Float16)e[kc][j];
        *(half8*)(ehg + (size_t)(((blk * 8 + kc) * 64) + lane) * 8) = h;
    }
    // row ssq: combine the 4 aoct groups (lane ^16, ^32)
    ssq += __shfl_xor(ssq, 16, 64);
    ssq += __shfl_xor(ssq, 32, 64);
    if (t < 16) ENORM[t] = ssq;
    __syncthreads();

    // ---- dist phase (verbatim R3 dist16, A-frags from e regs) ----
    floatx4 acc[4] = {}, accX[4] = {};
    #pragma unroll
    for (int kc = 0; kc < 8; ++kc) {
        half8 ah, al;
        #pragma unroll
        for (int j = 0; j < 8; ++j) {
            const _Float16 hi = (_Float16)e[kc][j];
            ah[j] = hi;
            al[j] = (_Float16)((e[kc][j] - (float)hi) * 2048.0f);
        }
        #pragma unroll
        for (int ni = 0; ni < 4; ++ni) {
            const size_t bb = (size_t)((kc * 16 + (w * 4 + ni)) * 64 + lane) * 8;
            const half8 bh = *(const half8*)(ch + bb);
            const half8 bl = *(const half8*)(cl + bb);
            acc[ni]  = __builtin_amdgcn_mfma_f32_16x16x32_f16(ah, bh, acc[ni], 0, 0, 0);
            accX[ni] = __builtin_amdgcn_mfma_f32_16x16x32_f16(ah, bl, accX[ni], 0, 0, 0);
            accX[ni] = __builtin_amdgcn_mfma_f32_16x16x32_f16(al, bh, accX[ni], 0, 0, 0);
        }
    }

    const float invs = 1.0f / 2048.0f;
    #pragma unroll
    for (int ni = 0; ni < 4; ++ni) {
        const int k = w * 64 + ni * 16 + (lane & 15);
        const float cn = cnorm[k];
        #pragma unroll
        for (int r = 0; r < 4; ++r) {
            const int rl = (lane >> 4) * 4 + r;
            const float S = acc[ni][r] + accX[ni][r] * invs;
            D[rl * 257 + k] = ENORM[rl] - 2.0f * S + cn;
        }
    }
    __syncthreads();

    #pragma unroll
    for (int rr = 0; rr < 4; ++rr) {
        const int r = w * 4 + rr;
        const float d0 = D[r * 257 + lane +   0];
        const float d1 = D[r * 257 + lane +  64];
        const float d2 = D[r * 257 + lane + 128];
        const float d3 = D[r * 257 + lane + 192];
        float mn = fminf(fminf(d0, d1), fminf(d2, d3));
        #pragma unroll
        for (int off = 32; off >= 1; off >>= 1) mn = fminf(mn, __shfl_xor(mn, off, 64));
        float s = expf(-ALPHA_F * (d0 - mn)) + expf(-ALPHA_F * (d1 - mn))
                + expf(-ALPHA_F * (d2 - mn)) + expf(-ALPHA_F * (d3 - mn));
        #pragma unroll
        for (int off = 32; off >= 1; off >>= 1) s += __shfl_xor(s, off, 64);
        if (lane == 0) { MINV[r] = mn; SUMV[r] = s; }
    }
    __syncthreads();

    const int b = t & 15, kg = t >> 4;
    const float mn = MINV[b], sv = SUMV[b];
    #pragma unroll
    for (int kk = 0; kk < 16; ++kk) {
        const int k = kk * 16 + kg;
        const float dv = D[b * 257 + k];
        out[(size_t)k * 8192 + b0 + b] = dv * expf(-ALPHA_F * (dv - mn)) / sv;
    }
}

// ============ recon — LDS-free, barrier-free register GEMM (unchanged) ======
__global__ __launch_bounds__(256) void recon_gemm(
    const _Float16* __restrict__ embh, const _Float16* __restrict__ Wdh,
    const float* __restrict__ b_dec, float* __restrict__ out)
{
    const int t = threadIdx.x, lane = t & 63, w = t >> 6;
    const int wm = w >> 1, wn = w & 1;
    const int nb = blockIdx.x, mb = blockIdx.y;

    floatx4 acc[4][4] = {};

    #pragma unroll
    for (int kc = 0; kc < 8; ++kc) {
        half8 a[4], b[4];
        #pragma unroll
        for (int mi = 0; mi < 4; ++mi)
            a[mi] = *(const half8*)(embh + (size_t)(((mb * 8 + wm * 4 + mi) * 8 + kc) * 64 + lane) * 8);
        #pragma unroll
        for (int ni = 0; ni < 4; ++ni)
            b[ni] = *(const half8*)(Wdh + (size_t)((kc * 128 + nb * 8 + wn * 4 + ni) * 64 + lane) * 8);
        #pragma unroll
        for (int mi = 0; mi < 4; ++mi)
            #pragma unroll
            for (int ni = 0; ni < 4; ++ni)
                acc[mi][ni] = __builtin_amdgcn_mfma_f32_16x16x32_f16(a[mi], b[ni], acc[mi][ni], 0, 0, 0);
    }

    #pragma unroll
    for (int ni = 0; ni < 4; ++ni) {
        const int col = nb * 128 + (wn * 4 + ni) * 16 + (lane & 15);
        const float bias = b_dec[col];
        #pragma unroll
        for (int mi = 0; mi < 4; ++mi) {
            const int rowBase = mb * 128 + (wm * 4 + mi) * 16 + (lane >> 4) * 4;
            #pragma unroll
            for (int r = 0; r < 4; ++r)
                out[(size_t)(rowBase + r) * 2048 + col] = acc[mi][ni][r] + bias;
        }
    }
}

// ================= launch ==================================================
extern "C" void kernel_launch(void* const* d_in, const int* in_sizes, int n_in,
                              void* d_out, int out_size, void* d_ws, size_t ws_size,
                              hipStream_t stream) {
    const float* x     = (const float*)d_in[0];   // [8192,2048]
    const float* W_enc = (const float*)d_in[1];   // [2048,256]
    const float* b_enc = (const float*)d_in[2];   // [256]
    const float* W_dec = (const float*)d_in[3];   // [256,2048]
    const float* b_dec = (const float*)d_in[4];   // [2048]
    const float* creps = (const float*)d_in[5];   // [256,256]

    float* out_w   = (float*)d_out;               // [256,8192]
    float* out_rec = out_w + (size_t)256 * 8192;  // [8192,2048]
    float* P       = out_rec;                     // split-K partials (32MB of 64MB)

    float*     cnorm = (float*)d_ws;                       // 1 KB
    _Float16*  embh  = (_Float16*)(cnorm + 256);           // 4 MB, frag-order
    _Float16*  Whf   = embh + (size_t)8192 * 256;          // 1 MB
    _Float16*  Wlf   = Whf + (size_t)2048 * 256;           // 1 MB
    _Float16*  Wdh   = Wlf + (size_t)2048 * 256;           // 1 MB
    _Float16*  crh   = Wdh + (size_t)256 * 2048;           // 128 KB
    _Float16*  crl   = crh + (size_t)256 * 256;            // 128 KB

    prep<<<608, 256, 0, stream>>>(W_enc, W_dec, creps, Whf, Wlf, Wdh, crh, crl, cnorm);

    emb_gemm<<<dim3(4, 128), 256, 0, stream>>>(x, Whf, Wlf, P);

    // fused finalize + dist + softmin (produces out_w and embh; no embf)
    dist_fused<<<512, 256, 0, stream>>>(P, b_enc, crh, crl, cnorm, embh, out_w);

    // reconstruction (output 1) — overwrites the partials region
    recon_gemm<<<dim3(16, 64), 256, 0, stream>>>(embh, Wdh, b_dec, out_rec);
}

// Round 11
// 181.562 us; speedup vs baseline: 1.1022x; 1.1022x over previous
//
#include <hip/hip_runtime.h>

#define ALPHA_F 1000.0f

typedef _Float16 half8 __attribute__((ext_vector_type(8)));
typedef float floatx4 __attribute__((ext_vector_type(4)));

// ============ fused prep: W_enc/W_dec/creps splits + cnorm (unchanged) =====
__global__ __launch_bounds__(256) void prep(
    const float* __restrict__ W_enc, const float* __restrict__ W_dec,
    const float* __restrict__ creps,
    _Float16* __restrict__ Wh, _Float16* __restrict__ Wl,
    _Float16* __restrict__ Wdh,
    _Float16* __restrict__ Ch, _Float16* __restrict__ Cl,
    float* __restrict__ cnorm)
{
    const int bid = blockIdx.x;
    if (bid < 256) {
        const int q = bid * 256 + threadIdx.x;
        const int n = q & 255, k8 = q >> 8;
        const int k = k8 * 8;
        half8 h, l;
        #pragma unroll
        for (int i = 0; i < 8; ++i) {
            const float v = W_enc[(size_t)(k + i) * 256 + n] * 256.0f;
            const _Float16 hi = (_Float16)v;
            h[i] = hi;
            l[i] = (_Float16)(v - (float)hi);
        }
        const int kc = k >> 5, nt = n >> 4;
        const int lane = (n & 15) | ((k8 & 3) << 4);
        const size_t idx = (size_t)((kc * 16 + nt) * 64 + lane) * 8;
        *(half8*)(Wh + idx) = h;
        *(half8*)(Wl + idx) = l;
    } else if (bid < 512) {
        const int q = (bid - 256) * 256 + threadIdx.x;
        const int n = q & 2047, k8 = q >> 11;
        const int k = k8 * 8;
        half8 h;
        #pragma unroll
        for (int i = 0; i < 8; ++i) h[i] = (_Float16)W_dec[(size_t)(k + i) * 2048 + n];
        const int kc = k8 >> 2, nt = n >> 4;
        const int lane = (n & 15) | ((k8 & 3) << 4);
        *(half8*)(Wdh + (size_t)((kc * 128 + nt) * 64 + lane) * 8) = h;
    } else if (bid < 544) {
        const int q = (bid - 512) * 256 + threadIdx.x;
        const int n = q & 255, j8 = q >> 8;
        const int j = j8 * 8;
        half8 h, l;
        #pragma unroll
        for (int i = 0; i < 8; ++i) {
            const float v = creps[(size_t)n * 256 + j + i];
            const _Float16 hi = (_Float16)v;
            h[i] = hi;
            l[i] = (_Float16)((v - (float)hi) * 2048.0f);
        }
        const int jc = j >> 5, nt = n >> 4;
        const int lane = (n & 15) | ((j8 & 3) << 4);
        const size_t idx = (size_t)((jc * 16 + nt) * 64 + lane) * 8;
        *(half8*)(Ch + idx) = h;
        *(half8*)(Cl + idx) = l;
    } else {
        const int wid = threadIdx.x >> 6, lane = threadIdx.x & 63;
        const int row = (bid - 544) * 4 + wid;
        const float4 v = *(const float4*)(creps + (size_t)row * 256 + lane * 4);
        float s = v.x * v.x + v.y * v.y + v.z * v.z + v.w * v.w;
        #pragma unroll
        for (int off = 32; off >= 1; off >>= 1) s += __shfl_xor(s, off, 64);
        if (lane == 0) cnorm[row] = s;
    }
}

// ============ emb partials — R3-exact (B from L2, raw barriers, 64-row) =====
__global__ __launch_bounds__(256) void emb_gemm(
    const float* __restrict__ x, const _Float16* __restrict__ Wh,
    const _Float16* __restrict__ Wl, float* __restrict__ P)
{
    __shared__ _Float16 Ah[2][2048], Al[2][2048];
    const int t = threadIdx.x, lane = t & 63, w = t >> 6;
    const int kk = blockIdx.x;
    const int mb = blockIdx.y;
    const int m0 = mb * 64;

    const int am = t >> 2, q = t & 3;
    const int aoff = (((am >> 4) * 64) + ((am & 15) | (q << 4))) * 8;
    const float* xP = x + (size_t)(m0 + am) * 2048 + kk * 512 + q * 8;

    const _Float16* bhP = Wh + (size_t)((kk * 256 + w * 4) * 64 + lane) * 8;
    const _Float16* blP = Wl + (size_t)((kk * 256 + w * 4) * 64 + lane) * 8;

    floatx4 acc[4][4] = {};
    half8 bh[4], bl[4];

    {
        const float4 v0 = *(const float4*)(xP);
        const float4 v1 = *(const float4*)(xP + 4);
        const float vv[8] = {v0.x, v0.y, v0.z, v0.w, v1.x, v1.y, v1.z, v1.w};
        half8 h8, l8;
        #pragma unroll
        for (int i = 0; i < 8; ++i) {
            const _Float16 hi = (_Float16)vv[i];
            h8[i] = hi;
            l8[i] = (_Float16)(vv[i] - (float)hi);
        }
        *(half8*)(&Ah[0][aoff]) = h8;
        *(half8*)(&Al[0][aoff]) = l8;
        #pragma unroll
        for (int ni = 0; ni < 4; ++ni) {
            bh[ni] = *(const half8*)(bhP + ni * 512);
            bl[ni] = *(const half8*)(blP + ni * 512);
        }
        asm volatile("s_waitcnt lgkmcnt(0)" ::: "memory");
        __builtin_amdgcn_sched_barrier(0);
        __builtin_amdgcn_s_barrier();
    }

    #pragma unroll 2
    for (int it = 0; it < 16; ++it) {
        const int buf = it & 1;

        float4 n0, n1;
        half8 nbh[4], nbl[4];
        if (it < 15) {
            n0 = *(const float4*)(xP + (it + 1) * 32);
            n1 = *(const float4*)(xP + (it + 1) * 32 + 4);
            #pragma unroll
            for (int ni = 0; ni < 4; ++ni) {
                nbh[ni] = *(const half8*)(bhP + (size_t)(it + 1) * 8192 + ni * 512);
                nbl[ni] = *(const half8*)(blP + (size_t)(it + 1) * 8192 + ni * 512);
            }
        }

        half8 ah[4], al[4];
        #pragma unroll
        for (int s = 0; s < 4; ++s) {
            ah[s] = *(const half8*)(&Ah[buf][(s * 64 + lane) * 8]);
            al[s] = *(const half8*)(&Al[buf][(s * 64 + lane) * 8]);
        }

        #pragma unroll
        for (int mi = 0; mi < 4; ++mi) {
            #pragma unroll
            for (int ni = 0; ni < 4; ++ni) {
                acc[mi][ni] = __builtin_amdgcn_mfma_f32_16x16x32_f16(ah[mi], bl[ni], acc[mi][ni], 0, 0, 0);
                acc[mi][ni] = __builtin_amdgcn_mfma_f32_16x16x32_f16(al[mi], bh[ni], acc[mi][ni], 0, 0, 0);
                acc[mi][ni] = __builtin_amdgcn_mfma_f32_16x16x32_f16(ah[mi], bh[ni], acc[mi][ni], 0, 0, 0);
            }
        }

        if (it < 15) {
            const float vv[8] = {n0.x, n0.y, n0.z, n0.w, n1.x, n1.y, n1.z, n1.w};
            half8 h8, l8;
            #pragma unroll
            for (int i = 0; i < 8; ++i) {
                const _Float16 hi = (_Float16)vv[i];
                h8[i] = hi;
                l8[i] = (_Float16)(vv[i] - (float)hi);
            }
            *(half8*)(&Ah[buf ^ 1][aoff]) = h8;
            *(half8*)(&Al[buf ^ 1][aoff]) = l8;
            #pragma unroll
            for (int ni = 0; ni < 4; ++ni) { bh[ni] = nbh[ni]; bl[ni] = nbl[ni]; }
            asm volatile("s_waitcnt lgkmcnt(0)" ::: "memory");
            __builtin_amdgcn_sched_barrier(0);
            __builtin_amdgcn_s_barrier();
        }
    }

    float* Pk = P + (size_t)kk * 2097152;
    #pragma unroll
    for (int mi = 0; mi < 4; ++mi) {
        #pragma unroll
        for (int ni = 0; ni < 4; ++ni) {
            const int col = w * 64 + ni * 16 + (lane & 15);
            const int rowBase = m0 + mi * 16 + (lane >> 4) * 4;
            #pragma unroll
            for (int r = 0; r < 4; ++r)
                Pk[(size_t)(rowBase + r) * 256 + col] = acc[mi][ni][r];
        }
    }
}

// ============ fused finalize + dist + softmin — wave-split phase A ==========
// R8's dist_fused had all 4 waves redundantly doing identical phase A (4x the
// load/convert instructions, pure latency). Now wave w handles only kc=2w,2w+1:
// P-sum (same kkp order -> e bit-identical), embh store (same slice as R8,
// bits identical), hi/lo conversion ONCE, fragments published via LDS
// (AhL/AlL[kc][lane], 16B/lane conflict-free). Dist-phase MFMA inputs are
// bit-identical to R8; only ssq summation order changed (per-row uniform D
// shift, cancels in d-mn; ~1e-3 on the dv prefactor, tolerance 10.0).
__global__ __launch_bounds__(256) void dist_fused(
    const float* __restrict__ P, const float* __restrict__ b_enc,
    const _Float16* __restrict__ ch, const _Float16* __restrict__ cl,
    const float* __restrict__ cnorm,
    _Float16* __restrict__ ehg, float* __restrict__ out)
{
    __shared__ _Float16 AhL[8 * 64 * 8], AlL[8 * 64 * 8];   // 8 KB each
    __shared__ float D[16 * 257];
    __shared__ float SSQP[4][16];
    __shared__ float MINV[16], SUMV[16];
    const int t = threadIdx.x, lane = t & 63, w = t >> 6;
    const int blk = blockIdx.x;
    const int b0 = blk * 16;
    const int arow16 = lane & 15, aoct = lane >> 4;

    // ---- phase A (wave-split): kc = 2w, 2w+1 only ----
    const float inv = 1.0f / 256.0f;
    float ssq = 0.0f;
    #pragma unroll
    for (int kq = 0; kq < 2; ++kq) {
        const int kc = w * 2 + kq;
        const float* p0 = P + (size_t)(b0 + arow16) * 256 + kc * 32 + aoct * 8;
        float4 v0 = *(const float4*)(p0);
        float4 v1 = *(const float4*)(p0 + 4);
        #pragma unroll
        for (int kkp = 1; kkp < 4; ++kkp) {
            const float* pk = p0 + (size_t)kkp * 2097152;
            const float4 a0 = *(const float4*)(pk);
            const float4 a1 = *(const float4*)(pk + 4);
            v0.x += a0.x; v0.y += a0.y; v0.z += a0.z; v0.w += a0.w;
            v1.x += a1.x; v1.y += a1.y; v1.z += a1.z; v1.w += a1.w;
        }
        const float4 bb0 = *(const float4*)(b_enc + kc * 32 + aoct * 8);
        const float4 bb1 = *(const float4*)(b_enc + kc * 32 + aoct * 8 + 4);
        float e[8];
        e[0] = v0.x * inv + bb0.x;
        e[1] = v0.y * inv + bb0.y;
        e[2] = v0.z * inv + bb0.z;
        e[3] = v0.w * inv + bb0.w;
        e[4] = v1.x * inv + bb1.x;
        e[5] = v1.y * inv + bb1.y;
        e[6] = v1.z * inv + bb1.z;
        e[7] = v1.w * inv + bb1.w;
        #pragma unroll
        for (int j = 0; j < 8; ++j) ssq += e[j] * e[j];
        // embh store (same slice wave w stored in R8 — bits identical)
        half8 h;
        #pragma unroll
        for (int j = 0; j < 8; ++j) h[j] = (_Float16)e[j];
        *(half8*)(ehg + (size_t)(((blk * 8 + kc) * 64) + lane) * 8) = h;
        // hi/lo fragment conversion (same formula), published once via LDS
        half8 ah, al;
        #pragma unroll
        for (int j = 0; j < 8; ++j) {
            const _Float16 hi = (_Float16)e[j];
            ah[j] = hi;
            al[j] = (_Float16)((e[j] - (float)hi) * 2048.0f);
        }
        *(half8*)(&AhL[(kc * 64 + lane) * 8]) = ah;
        *(half8*)(&AlL[(kc * 64 + lane) * 8]) = al;
    }
    // per-row ssq partial for this wave's 2 kc-blocks (combine 4 octs)
    ssq += __shfl_xor(ssq, 16, 64);
    ssq += __shfl_xor(ssq, 32, 64);
    if (lane < 16) SSQP[w][lane] = ssq;
    __syncthreads();

    // per-thread enorm for its 4 rl rows (LDS broadcast reads)
    float en[4];
    #pragma unroll
    for (int r = 0; r < 4; ++r) {
        const int rl = (lane >> 4) * 4 + r;
        en[r] = SSQP[0][rl] + SSQP[1][rl] + SSQP[2][rl] + SSQP[3][rl];
    }

    // ---- dist phase: A-frags from LDS; MFMA chains bit-identical ----
    floatx4 acc[4] = {}, accX[4] = {};
    #pragma unroll
    for (int kc = 0; kc < 8; ++kc) {
        const half8 ah = *(const half8*)(&AhL[(kc * 64 + lane) * 8]);
        const half8 al = *(const half8*)(&AlL[(kc * 64 + lane) * 8]);
        #pragma unroll
        for (int ni = 0; ni < 4; ++ni) {
            const size_t bb = (size_t)((kc * 16 + (w * 4 + ni)) * 64 + lane) * 8;
            const half8 bh = *(const half8*)(ch + bb);
            const half8 bl = *(const half8*)(cl + bb);
            acc[ni]  = __builtin_amdgcn_mfma_f32_16x16x32_f16(ah, bh, acc[ni], 0, 0, 0);
            accX[ni] = __builtin_amdgcn_mfma_f32_16x16x32_f16(ah, bl, accX[ni], 0, 0, 0);
            accX[ni] = __builtin_amdgcn_mfma_f32_16x16x32_f16(al, bh, accX[ni], 0, 0, 0);
        }
    }

    const float invs = 1.0f / 2048.0f;
    #pragma unroll
    for (int ni = 0; ni < 4; ++ni) {
        const int k = w * 64 + ni * 16 + (lane & 15);
        const float cn = cnorm[k];
        #pragma unroll
        for (int r = 0; r < 4; ++r) {
            const int rl = (lane >> 4) * 4 + r;
            const float S = acc[ni][r] + accX[ni][r] * invs;
            D[rl * 257 + k] = en[r] - 2.0f * S + cn;
        }
    }
    __syncthreads();

    #pragma unroll
    for (int rr = 0; rr < 4; ++rr) {
        const int r = w * 4 + rr;
        const float d0 = D[r * 257 + lane +   0];
        const float d1 = D[r * 257 + lane +  64];
        const float d2 = D[r * 257 + lane + 128];
        const float d3 = D[r * 257 + lane + 192];
        float mn = fminf(fminf(d0, d1), fminf(d2, d3));
        #pragma unroll
        for (int off = 32; off >= 1; off >>= 1) mn = fminf(mn, __shfl_xor(mn, off, 64));
        float s = expf(-ALPHA_F * (d0 - mn)) + expf(-ALPHA_F * (d1 - mn))
                + expf(-ALPHA_F * (d2 - mn)) + expf(-ALPHA_F * (d3 - mn));
        #pragma unroll
        for (int off = 32; off >= 1; off >>= 1) s += __shfl_xor(s, off, 64);
        if (lane == 0) { MINV[r] = mn; SUMV[r] = s; }
    }
    __syncthreads();

    const int b = t & 15, kg = t >> 4;
    const float mn = MINV[b], sv = SUMV[b];
    #pragma unroll
    for (int kk = 0; kk < 16; ++kk) {
        const int k = kk * 16 + kg;
        const float dv = D[b * 257 + k];
        out[(size_t)k * 8192 + b0 + b] = dv * expf(-ALPHA_F * (dv - mn)) / sv;
    }
}

// ============ recon — LDS-free, barrier-free register GEMM (unchanged) ======
__global__ __launch_bounds__(256) void recon_gemm(
    const _Float16* __restrict__ embh, const _Float16* __restrict__ Wdh,
    const float* __restrict__ b_dec, float* __restrict__ out)
{
    const int t = threadIdx.x, lane = t & 63, w = t >> 6;
    const int wm = w >> 1, wn = w & 1;
    const int nb = blockIdx.x, mb = blockIdx.y;

    floatx4 acc[4][4] = {};

    #pragma unroll
    for (int kc = 0; kc < 8; ++kc) {
        half8 a[4], b[4];
        #pragma unroll
        for (int mi = 0; mi < 4; ++mi)
            a[mi] = *(const half8*)(embh + (size_t)(((mb * 8 + wm * 4 + mi) * 8 + kc) * 64 + lane) * 8);
        #pragma unroll
        for (int ni = 0; ni < 4; ++ni)
            b[ni] = *(const half8*)(Wdh + (size_t)((kc * 128 + nb * 8 + wn * 4 + ni) * 64 + lane) * 8);
        #pragma unroll
        for (int mi = 0; mi < 4; ++mi)
            #pragma unroll
            for (int ni = 0; ni < 4; ++ni)
                acc[mi][ni] = __builtin_amdgcn_mfma_f32_16x16x32_f16(a[mi], b[ni], acc[mi][ni], 0, 0, 0);
    }

    #pragma unroll
    for (int ni = 0; ni < 4; ++ni) {
        const int col = nb * 128 + (wn * 4 + ni) * 16 + (lane & 15);
        const float bias = b_dec[col];
        #pragma unroll
        for (int mi = 0; mi < 4; ++mi) {
            const int rowBase = mb * 128 + (wm * 4 + mi) * 16 + (lane >> 4) * 4;
            #pragma unroll
            for (int r = 0; r < 4; ++r)
                out[(size_t)(rowBase + r) * 2048 + col] = acc[mi][ni][r] + bias;
        }
    }
}

// ================= launch ==================================================
extern "C" void kernel_launch(void* const* d_in, const int* in_sizes, int n_in,
                              void* d_out, int out_size, void* d_ws, size_t ws_size,
                              hipStream_t stream) {
    const float* x     = (const float*)d_in[0];   // [8192,2048]
    const float* W_enc = (const float*)d_in[1];   // [2048,256]
    const float* b_enc = (const float*)d_in[2];   // [256]
    const float* W_dec = (const float*)d_in[3];   // [256,2048]
    const float* b_dec = (const float*)d_in[4];   // [2048]
    const float* creps = (const float*)d_in[5];   // [256,256]

    float* out_w   = (float*)d_out;               // [256,8192]
    float* out_rec = out_w + (size_t)256 * 8192;  // [8192,2048]
    float* P       = out_rec;                     // split-K partials (32MB of 64MB)

    float*     cnorm = (float*)d_ws;                       // 1 KB
    _Float16*  embh  = (_Float16*)(cnorm + 256);           // 4 MB, frag-order
    _Float16*  Whf   = embh + (size_t)8192 * 256;          // 1 MB
    _Float16*  Wlf   = Whf + (size_t)2048 * 256;           // 1 MB
    _Float16*  Wdh   = Wlf + (size_t)2048 * 256;           // 1 MB
    _Float16*  crh   = Wdh + (size_t)256 * 2048;           // 128 KB
    _Float16*  crl   = crh + (size_t)256 * 256;            // 128 KB

    prep<<<608, 256, 0, stream>>>(W_enc, W_dec, creps, Whf, Wlf, Wdh, crh, crl, cnorm);

    emb_gemm<<<dim3(4, 128), 256, 0, stream>>>(x, Whf, Wlf, P);

    // fused finalize + dist + softmin (produces out_w and embh; no embf)
    dist_fused<<<512, 256, 0, stream>>>(P, b_enc, crh, crl, cnorm, embh, out_w);

    // reconstruction (output 1) — overwrites the partials region
    recon_gemm<<<dim3(16, 64), 256, 0, stream>>>(embh, Wdh, b_dec, out_rec);
}